// Round 1
// baseline (487.384 us; speedup 1.0000x reference)
//
#include <hip/hip_runtime.h>
#include <hip/hip_bf16.h>

// Problem: B=4, S=2048, F=512, E=512, H=8, DH=64
// out[b,s,h*64+d] = softmax_k( (q.k)/8 masked ) @ v, q = x@Wq+bq+etype, k = x@Wk+bk, v = x@Wv+bv
// Pipeline: f32 -> f16 cast, fused QKV MFMA GEMM, flash attention with online softmax.
// Workspace layout (needs ~33.5 MB):
//   xh  [8192][512] f16        @ 0        (8 MB)
//   wT  [3][512][512] f16      @ 8388608  (1.5 MB)   wT[z][n][k] = W_z[k][n]
//   Qh  [32][2048][64] f16     @ 9961472  (8 MB)
//   Kh  [32][2048][64] f16     @ 18350080 (8 MB)
//   Vt  [32][64][2048] f16     @ 26738688 (8 MB)     V transposed per head

typedef _Float16 f16x4 __attribute__((ext_vector_type(4)));
typedef float f32x4 __attribute__((ext_vector_type(4)));

#define MFMA16(a, b, c) __builtin_amdgcn_mfma_f32_16x16x16f16((a), (b), (c), 0, 0, 0)

constexpr int Bn = 4, Sn = 2048, Fn = 512, En = 512, Hn = 8, DHn = 64;

__global__ void cvt_f32_to_f16(const float* __restrict__ in, _Float16* __restrict__ out, int n4) {
    int i = blockIdx.x * blockDim.x + threadIdx.x;
    int stride = gridDim.x * blockDim.x;
    for (; i < n4; i += stride) {
        float4 v = reinterpret_cast<const float4*>(in)[i];
        f16x4 o = { (_Float16)v.x, (_Float16)v.y, (_Float16)v.z, (_Float16)v.w };
        reinterpret_cast<f16x4*>(out)[i] = o;
    }
}

// wT[z][n][k] = W_z[k][n]
__global__ void cvt_wT(const float* __restrict__ Wq, const float* __restrict__ Wk,
                       const float* __restrict__ Wv, _Float16* __restrict__ out) {
    const int z = blockIdx.z;
    const float* W = (z == 0) ? Wq : ((z == 1) ? Wk : Wv);
    _Float16* o = out + (size_t)z * Fn * En;
    __shared__ float tile[16][17];
    int n = blockIdx.x * 16 + threadIdx.x;
    int k = blockIdx.y * 16 + threadIdx.y;
    tile[threadIdx.y][threadIdx.x] = W[k * En + n];
    __syncthreads();
    int n2 = blockIdx.x * 16 + threadIdx.y;
    int k2 = blockIdx.y * 16 + threadIdx.x;
    o[(size_t)n2 * Fn + k2] = (_Float16)tile[threadIdx.x][threadIdx.y];
}

// Fused QKV GEMM. grid (64, 8, 3), block 256 (4 waves).
// Each wave: 32 rows x 64 cols via 2x4 16x16 MFMA fragments, K-loop over 512.
// A-frag: xh[m0+mt*16+(l&15)][k0+(l>>4)*4 + e]  (contiguous 4 f16)
// B-frag: wT[n0+nt*16+(l&15)][k0+(l>>4)*4 + e]  (contiguous 4 f16)
// D: row=(l>>4)*4+r, col=(l&15)   [m89-verified 16x16 layout]
__global__ __launch_bounds__(256) void qkv_gemm(
    const _Float16* __restrict__ xh, const _Float16* __restrict__ wT,
    const float* __restrict__ bq, const float* __restrict__ bk, const float* __restrict__ bv,
    const float* __restrict__ etype,
    _Float16* __restrict__ Qh, _Float16* __restrict__ Kh, _Float16* __restrict__ Vt) {
    const int z = blockIdx.z;
    const _Float16* W = wT + (size_t)z * Fn * En;
    const float* bias = (z == 0) ? bq : ((z == 1) ? bk : bv);

    const int wave = threadIdx.x >> 6;
    const int lane = threadIdx.x & 63;
    const int lr = lane & 15;
    const int lk = (lane >> 4) << 2;

    const int m0 = blockIdx.x * 128 + wave * 32;
    const int n0 = blockIdx.y * 64;

    f32x4 acc[2][4] = {};
#pragma unroll 4
    for (int k0 = 0; k0 < Fn; k0 += 16) {
        f16x4 a[2], bf[4];
#pragma unroll
        for (int mt = 0; mt < 2; ++mt)
            a[mt] = *reinterpret_cast<const f16x4*>(xh + (size_t)(m0 + mt * 16 + lr) * Fn + k0 + lk);
#pragma unroll
        for (int nt = 0; nt < 4; ++nt)
            bf[nt] = *reinterpret_cast<const f16x4*>(W + (size_t)(n0 + nt * 16 + lr) * Fn + k0 + lk);
#pragma unroll
        for (int mt = 0; mt < 2; ++mt)
#pragma unroll
            for (int nt = 0; nt < 4; ++nt)
                acc[mt][nt] = MFMA16(a[mt], bf[nt], acc[mt][nt]);
    }

#pragma unroll
    for (int mt = 0; mt < 2; ++mt) {
        const int rowb = m0 + mt * 16 + ((lane >> 4) << 2);
#pragma unroll
        for (int nt = 0; nt < 4; ++nt) {
            const int col = n0 + nt * 16 + lr;
            const int hh = col >> 6, dd = col & 63;
            const float bz = bias[col];
            if (z == 2) {
                // V: store transposed [bh][d][s]; r-values are 4 consecutive s -> one 8B store
                f16x4 vv;
#pragma unroll
                for (int r = 0; r < 4; ++r) vv[r] = (_Float16)(acc[mt][nt][r] + bz);
                const int bb = rowb >> 11, ss = rowb & 2047;
                *reinterpret_cast<f16x4*>(Vt + ((size_t)(bb * Hn + hh) * DHn + dd) * Sn + ss) = vv;
            } else {
                _Float16* dst = (z == 0) ? Qh : Kh;
#pragma unroll
                for (int r = 0; r < 4; ++r) {
                    const int row = rowb + r;
                    float v = acc[mt][nt][r] + bz;
                    if (z == 0) v += etype[(size_t)row * En + col];
                    const int bb = row >> 11, ss = row & 2047;
                    dst[((size_t)(bb * Hn + hh) * Sn + ss) * DHn + dd] = (_Float16)v;
                }
            }
        }
    }
}

// Flash attention. grid (16, 32), block 256 (4 waves x 32 q-rows = 128 q-rows/block).
__global__ __launch_bounds__(256) void attn(
    const _Float16* __restrict__ Qh, const _Float16* __restrict__ Kh,
    const _Float16* __restrict__ Vt, const int* __restrict__ mask,
    float* __restrict__ out) {
    const int bh = blockIdx.y;
    const int b = bh >> 3, h = bh & 7;
    const int wave = threadIdx.x >> 6;
    const int lane = threadIdx.x & 63;
    const int lr = lane & 15;
    const int lk = (lane >> 4) << 2;
    const int q0 = blockIdx.x * 128 + wave * 32;

    const _Float16* Qb = Qh + (size_t)bh * Sn * DHn;
    const _Float16* Kb = Kh + (size_t)bh * Sn * DHn;
    const _Float16* Vb = Vt + (size_t)bh * Sn * DHn;  // [64][2048]
    const int* mb = mask + b * Sn;

    // Q fragments held in registers for the whole KV loop
    f16x4 qf[2][4];
#pragma unroll
    for (int mt = 0; mt < 2; ++mt)
#pragma unroll
        for (int ks = 0; ks < 4; ++ks)
            qf[mt][ks] = *reinterpret_cast<const f16x4*>(Qb + (size_t)(q0 + mt * 16 + lr) * DHn + ks * 16 + lk);

    f32x4 oacc[2][4] = {};
    float mrun[2][4], lrun[2][4];
#pragma unroll
    for (int mt = 0; mt < 2; ++mt)
#pragma unroll
        for (int r = 0; r < 4; ++r) { mrun[mt][r] = -1e30f; lrun[mt][r] = 0.f; }

    // per-wave P buffer, XOR-swizzled (G4) to kill ds_read bank conflicts
    __shared__ __align__(16) _Float16 plds[4][32 * 64];
    char* pw = (char*)plds[wave];

    for (int t = 0; t < Sn / 64; ++t) {
        const int key0 = t * 64;
        f32x4 sc[2][4] = {};
#pragma unroll
        for (int ks = 0; ks < 4; ++ks) {
            f16x4 kf[4];
#pragma unroll
            for (int nt = 0; nt < 4; ++nt)
                kf[nt] = *reinterpret_cast<const f16x4*>(Kb + (size_t)(key0 + nt * 16 + lr) * DHn + ks * 16 + lk);
#pragma unroll
            for (int mt = 0; mt < 2; ++mt)
#pragma unroll
                for (int nt = 0; nt < 4; ++nt)
                    sc[mt][nt] = MFMA16(qf[mt][ks], kf[nt], sc[mt][nt]);
        }

        int km[4];
#pragma unroll
        for (int nt = 0; nt < 4; ++nt) km[nt] = mb[key0 + nt * 16 + lr];

#pragma unroll
        for (int mt = 0; mt < 2; ++mt)
#pragma unroll
            for (int nt = 0; nt < 4; ++nt)
#pragma unroll
                for (int r = 0; r < 4; ++r)
                    sc[mt][nt][r] = km[nt] ? sc[mt][nt][r] * 0.125f : -1e10f;

        float alpha[2][4];
#pragma unroll
        for (int mt = 0; mt < 2; ++mt)
#pragma unroll
            for (int r = 0; r < 4; ++r) {
                float v = fmaxf(fmaxf(sc[mt][0][r], sc[mt][1][r]), fmaxf(sc[mt][2][r], sc[mt][3][r]));
                v = fmaxf(v, __shfl_xor(v, 1));
                v = fmaxf(v, __shfl_xor(v, 2));
                v = fmaxf(v, __shfl_xor(v, 4));
                v = fmaxf(v, __shfl_xor(v, 8));
                const float mn = fmaxf(mrun[mt][r], v);
                alpha[mt][r] = __expf(mrun[mt][r] - mn);
                mrun[mt][r] = mn;
            }

#pragma unroll
        for (int mt = 0; mt < 2; ++mt)
#pragma unroll
            for (int r = 0; r < 4; ++r) {
                float ts = 0.f;
#pragma unroll
                for (int nt = 0; nt < 4; ++nt) {
                    float p = __expf(sc[mt][nt][r] - mrun[mt][r]);
                    sc[mt][nt][r] = p;
                    ts += p;
                }
                ts += __shfl_xor(ts, 1);
                ts += __shfl_xor(ts, 2);
                ts += __shfl_xor(ts, 4);
                ts += __shfl_xor(ts, 8);
                lrun[mt][r] = lrun[mt][r] * alpha[mt][r] + ts;
            }

#pragma unroll
        for (int mt = 0; mt < 2; ++mt)
#pragma unroll
            for (int dt = 0; dt < 4; ++dt)
#pragma unroll
                for (int r = 0; r < 4; ++r)
                    oacc[mt][dt][r] *= alpha[mt][r];

        // P (D-layout) -> LDS, swizzled; same-wave round trip, no block barrier needed
#pragma unroll
        for (int mt = 0; mt < 2; ++mt) {
            const int rowb = mt * 16 + ((lane >> 4) << 2);
#pragma unroll
            for (int r = 0; r < 4; ++r) {
                const int row = rowb + r;
                const int sw = (row & 7) << 4;
#pragma unroll
                for (int nt = 0; nt < 4; ++nt) {
                    const int byte = (row * 128 + (nt * 16 + lr) * 2) ^ sw;
                    *reinterpret_cast<_Float16*>(pw + byte) = (_Float16)sc[mt][nt][r];
                }
            }
        }
        asm volatile("s_waitcnt lgkmcnt(0)" ::: "memory");

#pragma unroll
        for (int ks = 0; ks < 4; ++ks) {
            f16x4 pa[2], vf[4];
#pragma unroll
            for (int mt = 0; mt < 2; ++mt) {
                const int row = mt * 16 + lr;
                const int byte = (row * 128 + (ks * 16 + lk) * 2) ^ ((row & 7) << 4);
                pa[mt] = *reinterpret_cast<const f16x4*>(pw + byte);
            }
#pragma unroll
            for (int dt = 0; dt < 4; ++dt)
                vf[dt] = *reinterpret_cast<const f16x4*>(Vb + (size_t)(dt * 16 + lr) * Sn + key0 + ks * 16 + lk);
#pragma unroll
            for (int mt = 0; mt < 2; ++mt)
#pragma unroll
                for (int dt = 0; dt < 4; ++dt)
                    oacc[mt][dt] = MFMA16(pa[mt], vf[dt], oacc[mt][dt]);
        }
    }

#pragma unroll
    for (int mt = 0; mt < 2; ++mt) {
#pragma unroll
        for (int r = 0; r < 4; ++r) {
            const int srow = q0 + mt * 16 + ((lane >> 4) << 2) + r;
            const float inv = (mb[srow] != 0) ? 1.0f / lrun[mt][r] : 0.0f;
#pragma unroll
            for (int dt = 0; dt < 4; ++dt)
                out[((size_t)(b * Sn + srow)) * En + h * DHn + dt * 16 + lr] = oacc[mt][dt][r] * inv;
        }
    }
}

extern "C" void kernel_launch(void* const* d_in, const int* in_sizes, int n_in,
                              void* d_out, int out_size, void* d_ws, size_t ws_size,
                              hipStream_t stream) {
    const float* x = (const float*)d_in[0];
    const float* etype = (const float*)d_in[1];
    const int* mask = (const int*)d_in[2];
    const float* Wq = (const float*)d_in[3];
    const float* bq = (const float*)d_in[4];
    const float* Wk = (const float*)d_in[5];
    const float* bk = (const float*)d_in[6];
    const float* Wv = (const float*)d_in[7];
    const float* bv = (const float*)d_in[8];
    float* out = (float*)d_out;

    char* ws = (char*)d_ws;
    _Float16* xh = (_Float16*)(ws + 0);
    _Float16* wT = (_Float16*)(ws + 8388608);
    _Float16* Qh = (_Float16*)(ws + 9961472);
    _Float16* Kh = (_Float16*)(ws + 18350080);
    _Float16* Vt = (_Float16*)(ws + 26738688);

    cvt_f32_to_f16<<<2048, 256, 0, stream>>>(x, xh, (Bn * Sn * Fn) / 4);
    cvt_wT<<<dim3(32, 32, 3), dim3(16, 16), 0, stream>>>(Wq, Wk, Wv, wT);
    qkv_gemm<<<dim3(64, 8, 3), 256, 0, stream>>>(xh, wT, bq, bk, bv, etype, Qh, Kh, Vt);
    attn<<<dim3(16, 32), 256, 0, stream>>>(Qh, Kh, Vt, mask, out);
}

// Round 2
// 302.342 us; speedup vs baseline: 1.6120x; 1.6120x over previous
//
#include <hip/hip_runtime.h>
#include <hip/hip_bf16.h>

// B=4, S=2048, F=512, E=512, H=8, DH=64
// Pipeline: f32->f16 cast, LDS-staged fused QKV MFMA GEMM (m97 recipe),
// flash attention with swapped-operand QK^T (register-local softmax + P->PV).
// Workspace:
//   xh  [8192][512] f16        @ 0        (8 MB)
//   wT  [3][512][512] f16      @ 8388608  (1.5 MB)   wT[z][n][k] = W_z[k][n]
//   Qh  [32][2048][64] f16     @ 9961472  (8 MB)
//   Kh  [32][2048][64] f16     @ 18350080 (8 MB)
//   Vt  [32][64][2048] f16     @ 26738688 (8 MB)     V transposed per head

typedef _Float16 f16x4 __attribute__((ext_vector_type(4)));
typedef _Float16 f16x8 __attribute__((ext_vector_type(8)));
typedef float f32x4 __attribute__((ext_vector_type(4)));

#define MFMA16(a, b, c) __builtin_amdgcn_mfma_f32_16x16x16f16((a), (b), (c), 0, 0, 0)
#define MFMA32(a, b, c) __builtin_amdgcn_mfma_f32_16x16x32_f16((a), (b), (c), 0, 0, 0)

constexpr int Bn = 4, Sn = 2048, Fn = 512, En = 512, Hn = 8, DHn = 64;

__global__ void cvt_f32_to_f16(const float* __restrict__ in, _Float16* __restrict__ out, int n4) {
    int i = blockIdx.x * blockDim.x + threadIdx.x;
    int stride = gridDim.x * blockDim.x;
    for (; i < n4; i += stride) {
        float4 v = reinterpret_cast<const float4*>(in)[i];
        f16x4 o = { (_Float16)v.x, (_Float16)v.y, (_Float16)v.z, (_Float16)v.w };
        reinterpret_cast<f16x4*>(out)[i] = o;
    }
}

// wT[z][n][k] = W_z[k][n]
__global__ void cvt_wT(const float* __restrict__ Wq, const float* __restrict__ Wk,
                       const float* __restrict__ Wv, _Float16* __restrict__ out) {
    const int z = blockIdx.z;
    const float* W = (z == 0) ? Wq : ((z == 1) ? Wk : Wv);
    _Float16* o = out + (size_t)z * Fn * En;
    __shared__ float tile[16][17];
    int n = blockIdx.x * 16 + threadIdx.x;
    int k = blockIdx.y * 16 + threadIdx.y;
    tile[threadIdx.y][threadIdx.x] = W[k * En + n];
    __syncthreads();
    int n2 = blockIdx.x * 16 + threadIdx.y;
    int k2 = blockIdx.y * 16 + threadIdx.x;
    o[(size_t)n2 * Fn + k2] = (_Float16)tile[threadIdx.x][threadIdx.y];
}

// Fused QKV GEMM, m97-style: 128x128 tile, BK=64, global_load_lds(16B) staging
// with XOR swizzle (byte ^= (row&7)<<4): pre-swizzled global source + swizzled
// ds_read_b128 (both-sides rule). 4 waves, each a 64x64 quadrant (4x4 frags),
// K=32 f16 MFMA. grid (64, 4, 3).
__global__ __launch_bounds__(256) void qkv_gemm(
    const _Float16* __restrict__ xh, const _Float16* __restrict__ wT,
    const float* __restrict__ bq, const float* __restrict__ bk, const float* __restrict__ bv,
    const float* __restrict__ etype,
    _Float16* __restrict__ Qh, _Float16* __restrict__ Kh, _Float16* __restrict__ Vt) {
    const int z = blockIdx.z;
    const _Float16* Wz = wT + (size_t)z * Fn * En;
    const float* bias = (z == 0) ? bq : ((z == 1) ? bk : bv);

    const int tid = threadIdx.x;
    const int wave = tid >> 6, lane = tid & 63;
    const int lr = lane & 15, hi = lane >> 4;
    const int wr = wave >> 1, wc = wave & 1;
    const int m0 = blockIdx.x * 128;
    const int n0 = blockIdx.y * 128;

    __shared__ __align__(16) char smem[32768];
    char* As = smem;
    char* Bs = smem + 16384;

    f32x4 acc[4][4] = {};

    const int inrow = (tid & 7) * 16;  // unswizzled byte-in-row this thread stages
    const int rowb = tid >> 3;         // base tile-row, +32 per it

    const char* xg = (const char*)xh;
    const char* wg = (const char*)Wz;

    for (int t = 0; t < 8; ++t) {
        const int k0b = t * 128;  // byte offset of this K-chunk within a 1024B row
        __syncthreads();          // previous compute done before overwrite
#pragma unroll
        for (int it = 0; it < 4; ++it) {
            const int row = rowb + it * 32;
            const int srccol = inrow ^ ((row & 7) << 4);  // inverse swizzle on source
            const char* ga = xg + (size_t)(m0 + row) * 1024 + k0b + srccol;
            const char* gb = wg + (size_t)(n0 + row) * 1024 + k0b + srccol;
            const int ldso = (it * 256 + tid) * 16;       // linear LDS dest
            __builtin_amdgcn_global_load_lds((const __attribute__((address_space(1))) void*)ga,
                                             (__attribute__((address_space(3))) void*)(As + ldso), 16, 0, 0);
            __builtin_amdgcn_global_load_lds((const __attribute__((address_space(1))) void*)gb,
                                             (__attribute__((address_space(3))) void*)(Bs + ldso), 16, 0, 0);
        }
        asm volatile("s_waitcnt vmcnt(0)" ::: "memory");
        __syncthreads();
#pragma unroll
        for (int ks = 0; ks < 2; ++ks) {
            f16x8 af[4], bf[4];
            const int kb = ks * 64 + hi * 16;
#pragma unroll
            for (int mt = 0; mt < 4; ++mt) {
                const int row = wr * 64 + mt * 16 + lr;
                af[mt] = *reinterpret_cast<const f16x8*>(As + row * 128 + (kb ^ ((row & 7) << 4)));
            }
#pragma unroll
            for (int nt = 0; nt < 4; ++nt) {
                const int row = wc * 64 + nt * 16 + lr;
                bf[nt] = *reinterpret_cast<const f16x8*>(Bs + row * 128 + (kb ^ ((row & 7) << 4)));
            }
#pragma unroll
            for (int mt = 0; mt < 4; ++mt)
#pragma unroll
                for (int nt = 0; nt < 4; ++nt)
                    acc[mt][nt] = MFMA32(af[mt], bf[nt], acc[mt][nt]);
        }
    }

#pragma unroll
    for (int mt = 0; mt < 4; ++mt) {
        const int gr0 = m0 + wr * 64 + mt * 16 + hi * 4;  // + r
#pragma unroll
        for (int nt = 0; nt < 4; ++nt) {
            const int col = n0 + wc * 64 + nt * 16 + lr;
            const int hh = col >> 6, dd = col & 63;
            const float bz = bias[col];
            if (z == 2) {
                f16x4 vv;
#pragma unroll
                for (int r = 0; r < 4; ++r) vv[r] = (_Float16)(acc[mt][nt][r] + bz);
                const int bb = gr0 >> 11, ss = gr0 & 2047;
                *reinterpret_cast<f16x4*>(Vt + ((size_t)(bb * Hn + hh) * DHn + dd) * Sn + ss) = vv;
            } else {
                _Float16* dst = (z == 0) ? Qh : Kh;
#pragma unroll
                for (int r = 0; r < 4; ++r) {
                    const int row = gr0 + r;
                    float v = acc[mt][nt][r] + bz;
                    if (z == 0) v += etype[(size_t)row * En + col];
                    const int bb = row >> 11, ss = row & 2047;
                    dst[((size_t)(bb * Hn + hh) * Sn + ss) * DHn + dd] = (_Float16)v;
                }
            }
        }
    }
}

// Flash attention, swapped-operand form. grid (16, 32), block 256 (4 waves x 32 q-rows).
// QK^T: scT = mfma(K, Q)  -> lane (l&15) owns q-row, keys live in regs (kt,r) + lane-groups
// PV:   O^T = mfma(V^T, P^T) -> softmax state / rescale / store all stay in l&15 domain.
// No LDS, no barriers, 2 shuffles per row-reduction.
__global__ __launch_bounds__(256) void attn(
    const _Float16* __restrict__ Qh, const _Float16* __restrict__ Kh,
    const _Float16* __restrict__ Vt, const int* __restrict__ mask,
    float* __restrict__ out) {
    const int bh = blockIdx.y;
    const int b = bh >> 3, h = bh & 7;
    const int wave = threadIdx.x >> 6, lane = threadIdx.x & 63;
    const int lr = lane & 15, hi = lane >> 4;
    const int q0 = blockIdx.x * 128 + wave * 32;

    const _Float16* Qb = Qh + (size_t)bh * Sn * DHn;
    const _Float16* Kb = Kh + (size_t)bh * Sn * DHn;
    const _Float16* Vb = Vt + (size_t)bh * Sn * DHn;  // [64][2048]
    const int* mb = mask + b * Sn;

    constexpr float CSC = 0.18033688011112042f;  // 0.125 * log2(e); softmax in base 2
    constexpr int NT = Sn / 64;

    // Q fragments (B-operand of swapped QK): col = l&15 = q-row, k = hi*8+e
    f16x8 qf[2][2];
#pragma unroll
    for (int mt = 0; mt < 2; ++mt)
#pragma unroll
        for (int ks = 0; ks < 2; ++ks)
            qf[mt][ks] = *reinterpret_cast<const f16x8*>(Qb + (q0 + mt * 16 + lr) * DHn + ks * 32 + hi * 8);

    f32x4 oaccT[4][2] = {};  // [dt][mt]: row = d-local (hi*4+r), col = q-row (l&15)
    float mrun[2] = {-1e30f, -1e30f}, lrun[2] = {0.f, 0.f};

    // K fragments (A-operand): row = l&15 = key, k = hi*8+e
    f16x8 kf[4][2];
#pragma unroll
    for (int kt = 0; kt < 4; ++kt)
#pragma unroll
        for (int ks = 0; ks < 2; ++ks)
            kf[kt][ks] = *reinterpret_cast<const f16x8*>(Kb + (kt * 16 + lr) * DHn + ks * 32 + hi * 8);

    for (int t = 0; t < NT; ++t) {
        const int key0 = t * 64;

        // prefetch next K tile + this tile's V and mask (in flight under QK+softmax)
        const int nk0 = (t + 1 < NT) ? key0 + 64 : 0;
        f16x8 kn[4][2];
#pragma unroll
        for (int kt = 0; kt < 4; ++kt)
#pragma unroll
            for (int ks = 0; ks < 2; ++ks)
                kn[kt][ks] = *reinterpret_cast<const f16x8*>(Kb + (nk0 + kt * 16 + lr) * DHn + ks * 32 + hi * 8);

        f16x4 vf[4][4];  // [ks][dt]: A-operand of PV: row = l&15 = d, k = key (hi*4+e)
#pragma unroll
        for (int ks = 0; ks < 4; ++ks)
#pragma unroll
            for (int dt = 0; dt < 4; ++dt)
                vf[ks][dt] = *reinterpret_cast<const f16x4*>(Vb + (dt * 16 + lr) * Sn + key0 + ks * 16 + hi * 4);

        int km[4][4];
#pragma unroll
        for (int kt = 0; kt < 4; ++kt) {
            const int4 kq = *reinterpret_cast<const int4*>(mb + key0 + kt * 16 + hi * 4);
            km[kt][0] = kq.x; km[kt][1] = kq.y; km[kt][2] = kq.z; km[kt][3] = kq.w;
        }

        // S^T = K·Q^T: D row = key-local (hi*4+r), col = q-row (l&15)
        f32x4 scT[4][2] = {};
#pragma unroll
        for (int ks = 0; ks < 2; ++ks)
#pragma unroll
            for (int kt = 0; kt < 4; ++kt)
#pragma unroll
                for (int mt = 0; mt < 2; ++mt)
                    scT[kt][mt] = MFMA32(kf[kt][ks], qf[mt][ks], scT[kt][mt]);

        // mask + prescale (base-2 domain): masked -> -1e30 (exp2 -> 0)
#pragma unroll
        for (int kt = 0; kt < 4; ++kt)
#pragma unroll
            for (int mt = 0; mt < 2; ++mt)
#pragma unroll
                for (int r = 0; r < 4; ++r)
                    scT[kt][mt][r] = km[kt][r] ? scT[kt][mt][r] * CSC : -1e30f;

        f16x4 pa[2][4];  // [mt][ks]: B-operand of PV: col = q-row (l&15), k = key
#pragma unroll
        for (int mt = 0; mt < 2; ++mt) {
            float mx = -1e30f;
#pragma unroll
            for (int kt = 0; kt < 4; ++kt)
#pragma unroll
                for (int r = 0; r < 4; ++r) mx = fmaxf(mx, scT[kt][mt][r]);
            mx = fmaxf(mx, __shfl_xor(mx, 16));
            mx = fmaxf(mx, __shfl_xor(mx, 32));
            const float mnew = fmaxf(mrun[mt], mx);
            const float alpha = exp2f(mrun[mt] - mnew);
            mrun[mt] = mnew;
            float ts = 0.f;
#pragma unroll
            for (int kt = 0; kt < 4; ++kt) {
                f16x4 ph;
#pragma unroll
                for (int r = 0; r < 4; ++r) {
                    const float p = exp2f(scT[kt][mt][r] - mnew);
                    ts += p;
                    ph[r] = (_Float16)p;
                }
                pa[mt][kt] = ph;
            }
            ts += __shfl_xor(ts, 16);
            ts += __shfl_xor(ts, 32);
            lrun[mt] = lrun[mt] * alpha + ts;
#pragma unroll
            for (int dt = 0; dt < 4; ++dt) oaccT[dt][mt] *= alpha;
        }

        // O^T += V^T · P^T
#pragma unroll
        for (int ks = 0; ks < 4; ++ks)
#pragma unroll
            for (int dt = 0; dt < 4; ++dt)
#pragma unroll
                for (int mt = 0; mt < 2; ++mt)
                    oaccT[dt][mt] = MFMA16(vf[ks][dt], pa[mt][ks], oaccT[dt][mt]);

#pragma unroll
        for (int kt = 0; kt < 4; ++kt)
#pragma unroll
            for (int ks = 0; ks < 2; ++ks)
                kf[kt][ks] = kn[kt][ks];
    }

    // epilogue: query-mask zeroing + 1/l, float4 stores (d contiguous in r)
#pragma unroll
    for (int mt = 0; mt < 2; ++mt) {
        const int srow = q0 + mt * 16 + lr;
        const float inv = (mb[srow] != 0) ? 1.0f / lrun[mt] : 0.0f;
#pragma unroll
        for (int dt = 0; dt < 4; ++dt) {
            f32x4 o = oaccT[dt][mt] * inv;
            *reinterpret_cast<f32x4*>(out + ((size_t)(b * Sn + srow)) * En + h * DHn + dt * 16 + hi * 4) = o;
        }
    }
}

extern "C" void kernel_launch(void* const* d_in, const int* in_sizes, int n_in,
                              void* d_out, int out_size, void* d_ws, size_t ws_size,
                              hipStream_t stream) {
    const float* x = (const float*)d_in[0];
    const float* etype = (const float*)d_in[1];
    const int* mask = (const int*)d_in[2];
    const float* Wq = (const float*)d_in[3];
    const float* bq = (const float*)d_in[4];
    const float* Wk = (const float*)d_in[5];
    const float* bk = (const float*)d_in[6];
    const float* Wv = (const float*)d_in[7];
    const float* bv = (const float*)d_in[8];
    float* out = (float*)d_out;

    char* ws = (char*)d_ws;
    _Float16* xh = (_Float16*)(ws + 0);
    _Float16* wT = (_Float16*)(ws + 8388608);
    _Float16* Qh = (_Float16*)(ws + 9961472);
    _Float16* Kh = (_Float16*)(ws + 18350080);
    _Float16* Vt = (_Float16*)(ws + 26738688);

    cvt_f32_to_f16<<<2048, 256, 0, stream>>>(x, xh, (Bn * Sn * Fn) / 4);
    cvt_wT<<<dim3(32, 32, 3), dim3(16, 16), 0, stream>>>(Wq, Wk, Wv, wT);
    qkv_gemm<<<dim3(64, 4, 3), 256, 0, stream>>>(xh, wT, bq, bk, bv, etype, Qh, Kh, Vt);
    attn<<<dim3(16, 32), 256, 0, stream>>>(Qh, Kh, Vt, mask, out);
}